// Round 1
// baseline (296.682 us; speedup 1.0000x reference)
//
#include <hip/hip_runtime.h>

// RoIAlign via TF crop_and_resize. Fixed problem shapes:
//   featuremap (N=2, C=256, H=200, W=304) fp32
//   rois       (M=2048, 5) fp32  [batch_id, x1, y1, x2, y2]
//   out        (M, C, 7, 7) fp32
#define RA_C   256
#define RA_H   200
#define RA_W   304
#define RA_HW  (RA_H * RA_W)        // 60800
#define RA_CHW (RA_C * RA_HW)       // 15564800
#define CROPN  7
#define CROP2  (CROPN * CROPN)      // 49
#define PER_M  (RA_C * CROP2)       // 12544

__global__ __launch_bounds__(256) void roialign_kernel(
    const float* __restrict__ fm, const float* __restrict__ rois,
    const float* __restrict__ scale_p, float* __restrict__ out)
{
    __shared__ int   s_offT[CROPN], s_offB[CROPN];   // yt*W, yb*W
    __shared__ float s_ylerp[CROPN], s_vy[CROPN];
    __shared__ int   s_xl[CROPN], s_xr[CROPN];
    __shared__ float s_xlerp[CROPN], s_vx[CROPN];
    __shared__ int   s_imgbase;

    const int t = threadIdx.x;
    const int m = blockIdx.x;

    if (t < 2 * CROPN) {
        // Replicate the reference's fp32 arithmetic exactly: no fma contraction
        // here, so validity comparisons (y>=0, y<=H-1) match numpy bit-for-bit.
        #pragma clang fp contract(off)
        {
            const float scale = scale_p[0];
            const float* r = rois + (size_t)m * 5;
            const int axis = (t < CROPN) ? 0 : 1;   // 0 = y, 1 = x
            const int k = axis ? (t - CROPN) : t;
            float lo, hi, szm1;
            if (axis == 0) { lo = r[2] * scale; hi = r[4] * scale; szm1 = (float)(RA_H - 1); }
            else           { lo = r[1] * scale; hi = r[3] * scale; szm1 = (float)(RA_W - 1); }
            // spacing = (hi-lo)/7 ; n0 = (lo + spacing/2 - 0.5)/(size-1)
            // nsz = spacing*6/(size-1) ; coord = n0*(size-1) + k*(((n0+nsz)-n0)*(size-1)/6)
            float sp   = (hi - lo) / 7.0f;
            float n0   = (lo + sp * 0.5f - 0.5f) / szm1;
            float nsz  = sp * 6.0f / szm1;
            float b2   = n0 + nsz;
            float d    = (b2 - n0) * szm1 / 6.0f;
            float coord = n0 * szm1 + (float)k * d;
            float fl = floorf(coord);
            float ce = ceilf(coord);
            float lerp = coord - fl;
            int lo_i = (int)fminf(fmaxf(fl, 0.0f), szm1);
            int hi_i = (int)fminf(fmaxf(ce, 0.0f), szm1);
            float valid = (coord >= 0.0f && coord <= szm1) ? 1.0f : 0.0f;
            if (axis == 0) {
                s_offT[k] = lo_i * RA_W; s_offB[k] = hi_i * RA_W;
                s_ylerp[k] = lerp; s_vy[k] = valid;
            } else {
                s_xl[k] = lo_i; s_xr[k] = hi_i;
                s_xlerp[k] = lerp; s_vx[k] = valid;
            }
        }
    }
    if (t == 63) {
        s_imgbase = (int)rois[(size_t)m * 5] * RA_CHW;  // batch index * C*H*W
    }
    __syncthreads();

    const float* __restrict__ img = fm + s_imgbase;
    float* __restrict__ outm = out + (size_t)m * PER_M;

    for (int e = t; e < PER_M; e += 256) {
        int c  = e / CROP2;
        int ij = e - c * CROP2;
        int i  = ij / CROPN;
        int j  = ij - i * CROPN;
        const float* __restrict__ p = img + (size_t)c * RA_HW;
        const int ot = s_offT[i], ob = s_offB[i];
        const int xl = s_xl[j],  xr = s_xr[j];
        const float xw = s_xlerp[j];
        const float yw = s_ylerp[i];
        const float v  = s_vy[i] * s_vx[j];
        float tl = p[ot + xl];
        float tr = p[ot + xr];
        float bl = p[ob + xl];
        float br = p[ob + xr];
        float top = tl + (tr - tl) * xw;
        float bot = bl + (br - bl) * xw;
        float res = (top + (bot - top) * yw) * v;
        outm[e] = res;
    }
}

extern "C" void kernel_launch(void* const* d_in, const int* in_sizes, int n_in,
                              void* d_out, int out_size, void* d_ws, size_t ws_size,
                              hipStream_t stream) {
    const float* fm    = (const float*)d_in[0];
    const float* rois  = (const float*)d_in[1];
    const float* scale = (const float*)d_in[2];
    float* out = (float*)d_out;
    const int M = in_sizes[1] / 5;   // 2048
    roialign_kernel<<<dim3(M), dim3(256), 0, stream>>>(fm, rois, scale, out);
}

// Round 2
// 294.371 us; speedup vs baseline: 1.0079x; 1.0079x over previous
//
#include <hip/hip_runtime.h>

// RoIAlign via TF crop_and_resize. Fixed problem shapes:
//   featuremap (N=2, C=256, H=200, W=304) fp32
//   rois       (M=2048, 5) fp32  [batch_id, x1, y1, x2, y2]
//   out        (M, C, 7, 7) fp32
//
// R2 restructure: block = (8 channels) x (32 boxes). XCD-pinned channel
// groups: XCD x owns channel groups 4x..4x+3 and sweeps box groups fastest,
// so the live channel-slice working set (~8ch x 2 batches x 243KB = 3.9MB)
// fits its 4MB L2 and cross-box pixel reuse stays on-die.
#define RA_C   256
#define RA_H   200
#define RA_W   304
#define RA_HW  (RA_H * RA_W)        // 60800
#define RA_CHW (RA_C * RA_HW)       // 15564800
#define CROPN  7
#define CROP2  (CROPN * CROPN)      // 49
#define OUT_M  (RA_C * CROP2)       // 12544 floats per box
#define BC     8                    // channels per block
#define BM     32                   // boxes per block
#define PER_BLK (BM * BC * CROP2)   // 12544 elements per block

__global__ __launch_bounds__(256) void roialign_kernel(
    const float* __restrict__ fm, const float* __restrict__ rois,
    const float* __restrict__ scale_p, float* __restrict__ out)
{
    __shared__ int   s_offT[BM][CROPN], s_offB[BM][CROPN];   // yt*W, yb*W
    __shared__ float s_ylerp[BM][CROPN], s_vy[BM][CROPN];
    __shared__ int   s_xl[BM][CROPN], s_xr[BM][CROPN];
    __shared__ float s_xlerp[BM][CROPN], s_vx[BM][CROPN];
    __shared__ int   s_imgbase[BM];

    const int t = threadIdx.x;

    // --- block -> (channel group, box group) with XCD pinning ---
    // gridDim.x = 32 * numBG. XCD = bid%8 owns cgs {4*xcd .. 4*xcd+3};
    // within an XCD the box-group index advances fastest.
    const int bid   = blockIdx.x;
    const int numBG = gridDim.x >> 5;          // M / BM
    const int xcd   = bid & 7;
    const int r     = bid >> 3;                // [0, 4*numBG)
    const int cgl   = r / numBG;               // [0, 4)
    const int bg    = r - cgl * numBG;         // [0, numBG)
    const int c0    = (xcd * 4 + cgl) * BC;    // first channel of group
    const int m0    = bg * BM;                 // first box of group

    // --- geometry for the BM boxes: BM*14 = 448 tasks over 256 threads ---
    for (int task = t; task < BM * 2 * CROPN; task += 256) {
        // Replicate the reference's fp32 arithmetic exactly (no contraction)
        // so validity comparisons (y>=0, y<=H-1) match numpy bit-for-bit.
        #pragma clang fp contract(off)
        {
            const int mm  = task / (2 * CROPN);
            const int k14 = task - mm * (2 * CROPN);
            const int axis = (k14 >= CROPN) ? 1 : 0;   // 0 = y, 1 = x
            const int k = axis ? (k14 - CROPN) : k14;
            const float scale = scale_p[0];
            const float* rr = rois + (size_t)(m0 + mm) * 5;
            if (k14 == 0) s_imgbase[mm] = (int)rr[0] * RA_CHW;
            float lo, hi, szm1;
            if (axis == 0) { lo = rr[2] * scale; hi = rr[4] * scale; szm1 = (float)(RA_H - 1); }
            else           { lo = rr[1] * scale; hi = rr[3] * scale; szm1 = (float)(RA_W - 1); }
            float sp   = (hi - lo) / 7.0f;
            float n0   = (lo + sp * 0.5f - 0.5f) / szm1;
            float nsz  = sp * 6.0f / szm1;
            float b2   = n0 + nsz;
            float d    = (b2 - n0) * szm1 / 6.0f;
            float coord = n0 * szm1 + (float)k * d;
            float fl = floorf(coord);
            float ce = ceilf(coord);
            float lerp = coord - fl;
            int lo_i = (int)fminf(fmaxf(fl, 0.0f), szm1);
            int hi_i = (int)fminf(fmaxf(ce, 0.0f), szm1);
            float valid = (coord >= 0.0f && coord <= szm1) ? 1.0f : 0.0f;
            if (axis == 0) {
                s_offT[mm][k] = lo_i * RA_W; s_offB[mm][k] = hi_i * RA_W;
                s_ylerp[mm][k] = lerp; s_vy[mm][k] = valid;
            } else {
                s_xl[mm][k] = lo_i; s_xr[mm][k] = hi_i;
                s_xlerp[mm][k] = lerp; s_vx[mm][k] = valid;
            }
        }
    }
    __syncthreads();

    // --- main sweep: BM boxes x BC channels x 49 samples ---
    for (int e = t; e < PER_BLK; e += 256) {
        int mm  = e / (BC * CROP2);            // box within group
        int rem = e - mm * (BC * CROP2);
        int cc  = rem / CROP2;                 // channel within group
        int ij  = rem - cc * CROP2;
        int i   = ij / CROPN;
        int j   = ij - i * CROPN;
        const float* __restrict__ p =
            fm + (size_t)s_imgbase[mm] + (size_t)(c0 + cc) * RA_HW;
        const int ot = s_offT[mm][i], ob = s_offB[mm][i];
        const int xl = s_xl[mm][j],  xr = s_xr[mm][j];
        const float xw = s_xlerp[mm][j];
        const float yw = s_ylerp[mm][i];
        const float v  = s_vy[mm][i] * s_vx[mm][j];
        float tl = p[ot + xl];
        float tr = p[ot + xr];
        float bl = p[ob + xl];
        float br = p[ob + xr];
        float top = tl + (tr - tl) * xw;
        float bot = bl + (br - bl) * xw;
        float res = (top + (bot - top) * yw) * v;
        out[(size_t)(m0 + mm) * OUT_M + (size_t)(c0 + cc) * CROP2 + ij] = res;
    }
}

extern "C" void kernel_launch(void* const* d_in, const int* in_sizes, int n_in,
                              void* d_out, int out_size, void* d_ws, size_t ws_size,
                              hipStream_t stream) {
    const float* fm    = (const float*)d_in[0];
    const float* rois  = (const float*)d_in[1];
    const float* scale = (const float*)d_in[2];
    float* out = (float*)d_out;
    const int M = in_sizes[1] / 5;             // 2048
    const int numBG = M / BM;                  // 64
    roialign_kernel<<<dim3(32 * numBG), dim3(256), 0, stream>>>(fm, rois, scale, out);
}